// Round 1
// baseline (888.487 us; speedup 1.0000x reference)
//
#include <hip/hip_runtime.h>
#include <hip/hip_bf16.h>

#define NUM_EXPERTS 8
#define HIDDEN 2048
#define INTER 1024
#define NTOK 4096
#define TOPK 2
#define BM 128
#define BK 64
#define MPAD 9216      // 72 tiles of 128; >= 8192 + 8*127
#define TILES_M 72

typedef __attribute__((ext_vector_type(8))) short bf16x8;
typedef __attribute__((ext_vector_type(4))) float f32x4;

static __device__ __forceinline__ unsigned short f2bf(float f) {
    unsigned u = __builtin_bit_cast(unsigned, f);
    unsigned rounding = 0x7fffu + ((u >> 16) & 1u);
    u += rounding;
    return (unsigned short)(u >> 16);
}

// ---------------- Router ----------------
__global__ __launch_bounds__(256) void router_kernel(
    const float* __restrict__ x, const float* __restrict__ Wr,
    float* __restrict__ logits_out, int* __restrict__ topk_idx,
    float* __restrict__ topk_w, int* __restrict__ cnt)
{
    int t = blockIdx.x;
    const float* xr = x + (size_t)t * HIDDEN;
    float acc[NUM_EXPERTS];
#pragma unroll
    for (int e = 0; e < NUM_EXPERTS; ++e) acc[e] = 0.f;
    for (int d = threadIdx.x; d < HIDDEN; d += 256) {
        float xv = xr[d];
#pragma unroll
        for (int e = 0; e < NUM_EXPERTS; ++e)
            acc[e] += xv * Wr[e * HIDDEN + d];
    }
#pragma unroll
    for (int e = 0; e < NUM_EXPERTS; ++e)
        for (int o = 32; o > 0; o >>= 1)
            acc[e] += __shfl_xor(acc[e], o, 64);
    __shared__ float red[4][NUM_EXPERTS];
    int wid = threadIdx.x >> 6, lid = threadIdx.x & 63;
    if (lid == 0) {
#pragma unroll
        for (int e = 0; e < NUM_EXPERTS; ++e) red[wid][e] = acc[e];
    }
    __syncthreads();
    if (threadIdx.x == 0) {
        float l[NUM_EXPERTS];
#pragma unroll
        for (int e = 0; e < NUM_EXPERTS; ++e) {
            l[e] = (red[0][e] + red[1][e] + red[2][e] + red[3][e]); // TEMP = 1.0
            logits_out[(size_t)t * NUM_EXPERTS + e] = l[e];
        }
        int i0 = 0; float v0 = l[0];
#pragma unroll
        for (int e = 1; e < NUM_EXPERTS; ++e)
            if (l[e] > v0) { v0 = l[e]; i0 = e; }
        int i1 = -1; float v1 = -1e30f;
#pragma unroll
        for (int e = 0; e < NUM_EXPERTS; ++e) {
            if (e == i0) continue;
            if (i1 < 0 || l[e] > v1) { v1 = l[e]; i1 = e; }
        }
        float e1 = expf(v1 - v0);
        float inv = 1.0f / (1.0f + e1);
        float w0 = inv, w1 = e1 * inv;
        topk_idx[t * 2 + 0] = i0;
        topk_idx[t * 2 + 1] = i1;
        topk_w[t * 2 + 0] = w0;
        topk_w[t * 2 + 1] = w1;
        atomicAdd(&cnt[i0], 1);
        atomicAdd(&cnt[i1], 1);
    }
}

// ---------------- Setup (scan + init) ----------------
__global__ __launch_bounds__(256) void setup_kernel(
    const int* __restrict__ cnt, int* __restrict__ cursor,
    int* __restrict__ tile_expert, int* __restrict__ row_token,
    float* __restrict__ row_weight)
{
    if (threadIdx.x == 0) {
        int tot = 0;
        for (int e = 0; e < NUM_EXPERTS; ++e) {
            cursor[e] = tot;
            int pc = ((cnt[e] + BM - 1) / BM) * BM;
            int t0 = tot / BM, t1 = (tot + pc) / BM;
            for (int t = t0; t < t1; ++t) tile_expert[t] = e;
            tot += pc;
        }
        for (int t = tot / BM; t < TILES_M; ++t) tile_expert[t] = 0;
    }
    for (int r = threadIdx.x; r < MPAD; r += 256) {
        row_token[r] = -1;
        row_weight[r] = 0.f;
    }
}

// ---------------- Scatter ----------------
__global__ __launch_bounds__(256) void scatter_kernel(
    const int* __restrict__ topk_idx, const float* __restrict__ topk_w,
    int* __restrict__ cursor, int* __restrict__ row_token,
    float* __restrict__ row_weight)
{
    int t = blockIdx.x * 256 + threadIdx.x;
    if (t >= NTOK) return;
#pragma unroll
    for (int k = 0; k < TOPK; ++k) {
        int e = topk_idx[t * 2 + k];
        float w = topk_w[t * 2 + k];
        int pos = atomicAdd(&cursor[e], 1);
        row_token[pos] = t;
        row_weight[pos] = w;
    }
}

// ---------------- GEMM1: H = silu(Xp Wg^T) * (Xp Wu^T) ----------------
__global__ __launch_bounds__(256) void gemm1_kernel(
    const float* __restrict__ x, const float* __restrict__ Wg,
    const float* __restrict__ Wu, const int* __restrict__ row_token,
    const int* __restrict__ tile_expert, ushort* __restrict__ H)
{
    int mtile = blockIdx.x, ntile = blockIdx.y;
    int e = tile_expert[mtile];
    __shared__ ushort As[BM * BK];
    __shared__ ushort Bgs[BM * BK];
    __shared__ ushort Bus[BM * BK];
    __shared__ int s_tok[BM];
    int tid = threadIdx.x;
    if (tid < BM) s_tok[tid] = row_token[mtile * BM + tid];

    const float* WgB = Wg + (size_t)e * INTER * HIDDEN + (size_t)(ntile * BM) * HIDDEN;
    const float* WuB = Wu + (size_t)e * INTER * HIDDEN + (size_t)(ntile * BM) * HIDDEN;

    f32x4 accG[4][4], accU[4][4];
#pragma unroll
    for (int mi = 0; mi < 4; ++mi)
#pragma unroll
        for (int nj = 0; nj < 4; ++nj) {
            accG[mi][nj] = (f32x4){0.f, 0.f, 0.f, 0.f};
            accU[mi][nj] = (f32x4){0.f, 0.f, 0.f, 0.f};
        }

    int lid = tid & 63, wid = tid >> 6;
    int wm = (wid >> 1) * 64, wn = (wid & 1) * 64;
    int lrow = lid & 15, kg = lid >> 4;

    for (int kk = 0; kk < HIDDEN; kk += BK) {
        __syncthreads();
        // stage A (gather + convert)
#pragma unroll
        for (int it = 0; it < 8; ++it) {
            int i = it * 256 + tid;
            int r = i >> 4, c = (i & 15) * 4;
            int tok = s_tok[r];
            float4 v = make_float4(0.f, 0.f, 0.f, 0.f);
            if (tok >= 0)
                v = *(const float4*)(x + (size_t)tok * HIDDEN + kk + c);
            uint2 p;
            p.x = (unsigned)f2bf(v.x) | ((unsigned)f2bf(v.y) << 16);
            p.y = (unsigned)f2bf(v.z) | ((unsigned)f2bf(v.w) << 16);
            int idx = (r * BK + c) ^ ((r & 7) << 3);
            *(uint2*)&As[idx] = p;
        }
        // stage Bg, Bu (convert)
#pragma unroll
        for (int it = 0; it < 8; ++it) {
            int i = it * 256 + tid;
            int r = i >> 4, c = (i & 15) * 4;
            float4 vg = *(const float4*)(WgB + (size_t)r * HIDDEN + kk + c);
            float4 vu = *(const float4*)(WuB + (size_t)r * HIDDEN + kk + c);
            int idx = (r * BK + c) ^ ((r & 7) << 3);
            uint2 pg, pu;
            pg.x = (unsigned)f2bf(vg.x) | ((unsigned)f2bf(vg.y) << 16);
            pg.y = (unsigned)f2bf(vg.z) | ((unsigned)f2bf(vg.w) << 16);
            pu.x = (unsigned)f2bf(vu.x) | ((unsigned)f2bf(vu.y) << 16);
            pu.y = (unsigned)f2bf(vu.z) | ((unsigned)f2bf(vu.w) << 16);
            *(uint2*)&Bgs[idx] = pg;
            *(uint2*)&Bus[idx] = pu;
        }
        __syncthreads();
#pragma unroll
        for (int ks = 0; ks < 2; ++ks) {
            bf16x8 a[4], bg[4], bu[4];
            int kcol = ks * 32 + kg * 8;
#pragma unroll
            for (int mi = 0; mi < 4; ++mi) {
                int r = wm + mi * 16 + lrow;
                a[mi] = *(const bf16x8*)&As[(r * BK + kcol) ^ ((r & 7) << 3)];
            }
#pragma unroll
            for (int nj = 0; nj < 4; ++nj) {
                int r = wn + nj * 16 + lrow;
                int idx = (r * BK + kcol) ^ ((r & 7) << 3);
                bg[nj] = *(const bf16x8*)&Bgs[idx];
                bu[nj] = *(const bf16x8*)&Bus[idx];
            }
#pragma unroll
            for (int mi = 0; mi < 4; ++mi)
#pragma unroll
                for (int nj = 0; nj < 4; ++nj) {
                    accG[mi][nj] = __builtin_amdgcn_mfma_f32_16x16x32_bf16(
                        a[mi], bg[nj], accG[mi][nj], 0, 0, 0);
                    accU[mi][nj] = __builtin_amdgcn_mfma_f32_16x16x32_bf16(
                        a[mi], bu[nj], accU[mi][nj], 0, 0, 0);
                }
        }
    }
    // epilogue: h = silu(g) * u -> bf16 H[row][col]
#pragma unroll
    for (int mi = 0; mi < 4; ++mi)
#pragma unroll
        for (int nj = 0; nj < 4; ++nj)
#pragma unroll
            for (int q = 0; q < 4; ++q) {
                int row = mtile * BM + wm + mi * 16 + kg * 4 + q;
                int col = ntile * BM + wn + nj * 16 + lrow;
                float g = accG[mi][nj][q], u = accU[mi][nj][q];
                float h = (g / (1.0f + expf(-g))) * u;
                H[(size_t)row * INTER + col] = f2bf(h);
            }
}

// ---------------- GEMM2: out += w * (H Wd^T) ----------------
__global__ __launch_bounds__(256) void gemm2_kernel(
    const ushort* __restrict__ H, const float* __restrict__ Wd,
    const int* __restrict__ row_token, const float* __restrict__ row_weight,
    const int* __restrict__ tile_expert, float* __restrict__ out)
{
    int mtile = blockIdx.x, ntile = blockIdx.y;
    int e = tile_expert[mtile];
    __shared__ ushort As[BM * BK];
    __shared__ ushort Bs[BM * BK];
    __shared__ int s_tok[BM];
    __shared__ float s_w[BM];
    int tid = threadIdx.x;
    if (tid < BM) {
        s_tok[tid] = row_token[mtile * BM + tid];
        s_w[tid] = row_weight[mtile * BM + tid];
    }

    const float* WdB = Wd + (size_t)e * HIDDEN * INTER + (size_t)(ntile * BM) * INTER;

    f32x4 acc[4][4];
#pragma unroll
    for (int mi = 0; mi < 4; ++mi)
#pragma unroll
        for (int nj = 0; nj < 4; ++nj)
            acc[mi][nj] = (f32x4){0.f, 0.f, 0.f, 0.f};

    int lid = tid & 63, wid = tid >> 6;
    int wm = (wid >> 1) * 64, wn = (wid & 1) * 64;
    int lrow = lid & 15, kg = lid >> 4;

    for (int kk = 0; kk < INTER; kk += BK) {
        __syncthreads();
        // stage A from H (already bf16): 16B per thread per iter
#pragma unroll
        for (int it = 0; it < 4; ++it) {
            int i = it * 256 + tid;
            int r = i >> 3, c = (i & 7) * 8;
            uint4 v = *(const uint4*)(H + (size_t)(mtile * BM + r) * INTER + kk + c);
            int idx = (r * BK + c) ^ ((r & 7) << 3);
            *(uint4*)&As[idx] = v;
        }
        // stage B from Wd (convert)
#pragma unroll
        for (int it = 0; it < 8; ++it) {
            int i = it * 256 + tid;
            int r = i >> 4, c = (i & 15) * 4;
            float4 v = *(const float4*)(WdB + (size_t)r * INTER + kk + c);
            int idx = (r * BK + c) ^ ((r & 7) << 3);
            uint2 p;
            p.x = (unsigned)f2bf(v.x) | ((unsigned)f2bf(v.y) << 16);
            p.y = (unsigned)f2bf(v.z) | ((unsigned)f2bf(v.w) << 16);
            *(uint2*)&Bs[idx] = p;
        }
        __syncthreads();
#pragma unroll
        for (int ks = 0; ks < 2; ++ks) {
            bf16x8 a[4], b[4];
            int kcol = ks * 32 + kg * 8;
#pragma unroll
            for (int mi = 0; mi < 4; ++mi) {
                int r = wm + mi * 16 + lrow;
                a[mi] = *(const bf16x8*)&As[(r * BK + kcol) ^ ((r & 7) << 3)];
            }
#pragma unroll
            for (int nj = 0; nj < 4; ++nj) {
                int r = wn + nj * 16 + lrow;
                b[nj] = *(const bf16x8*)&Bs[(r * BK + kcol) ^ ((r & 7) << 3)];
            }
#pragma unroll
            for (int mi = 0; mi < 4; ++mi)
#pragma unroll
                for (int nj = 0; nj < 4; ++nj)
                    acc[mi][nj] = __builtin_amdgcn_mfma_f32_16x16x32_bf16(
                        a[mi], b[nj], acc[mi][nj], 0, 0, 0);
        }
    }
    // epilogue: scatter-add weighted result
#pragma unroll
    for (int mi = 0; mi < 4; ++mi)
#pragma unroll
        for (int nj = 0; nj < 4; ++nj)
#pragma unroll
            for (int q = 0; q < 4; ++q) {
                int lrow_local = wm + mi * 16 + kg * 4 + q;
                int tok = s_tok[lrow_local];
                if (tok >= 0) {
                    int col = ntile * BM + wn + nj * 16 + lrow;
                    float val = acc[mi][nj][q] * s_w[lrow_local];
                    atomicAdd(&out[(size_t)tok * HIDDEN + col], val);
                }
            }
}

extern "C" void kernel_launch(void* const* d_in, const int* in_sizes, int n_in,
                              void* d_out, int out_size, void* d_ws, size_t ws_size,
                              hipStream_t stream) {
    const float* x  = (const float*)d_in[0];
    const float* Wr = (const float*)d_in[1];
    const float* Wg = (const float*)d_in[2];
    const float* Wu = (const float*)d_in[3];
    const float* Wd = (const float*)d_in[4];
    float* out = (float*)d_out;
    float* logits = out + (size_t)NTOK * HIDDEN;

    char* ws = (char*)d_ws;
    int*   cnt         = (int*)(ws + 0);
    int*   cursor      = (int*)(ws + 32);
    int*   tile_expert = (int*)(ws + 64);
    int*   topk_idx    = (int*)(ws + 512);
    float* topk_w      = (float*)(ws + 512 + 32768);
    int*   row_token   = (int*)(ws + 512 + 65536);
    float* row_weight  = (float*)(ws + 512 + 65536 + 36864);
    ushort* H          = (ushort*)(ws + 147456);

    hipMemsetAsync(d_out, 0, (size_t)out_size * sizeof(float), stream);
    hipMemsetAsync(d_ws, 0, 64, stream);

    router_kernel<<<NTOK, 256, 0, stream>>>(x, Wr, logits, topk_idx, topk_w, cnt);
    setup_kernel<<<1, 256, 0, stream>>>(cnt, cursor, tile_expert, row_token, row_weight);
    scatter_kernel<<<NTOK / 256, 256, 0, stream>>>(topk_idx, topk_w, cursor, row_token, row_weight);
    gemm1_kernel<<<dim3(TILES_M, INTER / BM), 256, 0, stream>>>(x, Wg, Wu, row_token, tile_expert, H);
    gemm2_kernel<<<dim3(TILES_M, HIDDEN / BM), 256, 0, stream>>>(H, Wd, row_token, row_weight, tile_expert, out);
}

// Round 3
// 676.174 us; speedup vs baseline: 1.3140x; 1.3140x over previous
//
#include <hip/hip_runtime.h>
#include <hip/hip_bf16.h>

#define NUM_EXPERTS 8
#define HIDDEN 2048
#define INTER 1024
#define NTOK 4096
#define TOPK 2
#define BM 128
#define BK 64
#define MPAD 9216      // 72 tiles of 128; >= 8192 + 8*127
#define TILES_M 72

typedef __attribute__((ext_vector_type(8))) short bf16x8;
typedef __attribute__((ext_vector_type(4))) float f32x4;

typedef const __attribute__((address_space(1))) unsigned char* gptr_u8;
typedef __attribute__((address_space(3))) unsigned char* lptr_u8;

static __device__ __forceinline__ void gload_lds16(const void* g, void* l) {
    __builtin_amdgcn_global_load_lds((gptr_u8)g, (lptr_u8)l, 16, 0, 0);
}

static __device__ __forceinline__ unsigned short f2bf(float f) {
    unsigned u = __builtin_bit_cast(unsigned, f);
    unsigned rounding = 0x7fffu + ((u >> 16) & 1u);
    u += rounding;
    return (unsigned short)(u >> 16);
}
static __device__ __forceinline__ unsigned pack2(float a, float b) {
    return (unsigned)f2bf(a) | ((unsigned)f2bf(b) << 16);
}

// ---------------- Weight convert: fp32 -> bf16 (one pass, fast path only) ---
__global__ __launch_bounds__(256) void convert_kernel(
    const float* __restrict__ Wg, const float* __restrict__ Wu,
    const float* __restrict__ Wd, ushort* __restrict__ Wgb,
    ushort* __restrict__ Wub, ushort* __restrict__ Wdb)
{
    const float* src = (blockIdx.y == 0) ? Wg : (blockIdx.y == 1) ? Wu : Wd;
    ushort* dst = (blockIdx.y == 0) ? Wgb : (blockIdx.y == 1) ? Wub : Wdb;
    size_t idx = (size_t)blockIdx.x * 256 + threadIdx.x;
#pragma unroll
    for (int i = 0; i < 4; ++i) {
        size_t p = idx + (size_t)i * 1048576;
        float4 v = ((const float4*)src)[p];
        uint2 u;
        u.x = pack2(v.x, v.y);
        u.y = pack2(v.z, v.w);
        ((uint2*)dst)[p] = u;
    }
}

// ---------------- Router (+ optional x fp32->bf16) ----------------
__global__ __launch_bounds__(256) void router_kernel(
    const float* __restrict__ x, const float* __restrict__ Wr,
    ushort* __restrict__ xbf, float* __restrict__ logits_out,
    int* __restrict__ topk_idx, float* __restrict__ topk_w, int* __restrict__ cnt)
{
    int t = blockIdx.x;
    const float4* xr = (const float4*)(x + (size_t)t * HIDDEN);
    float acc[NUM_EXPERTS];
#pragma unroll
    for (int e = 0; e < NUM_EXPERTS; ++e) acc[e] = 0.f;
#pragma unroll
    for (int i = 0; i < 2; ++i) {
        int d4 = threadIdx.x + i * 256;
        float4 xv = xr[d4];
        if (xbf) {
            uint2 p;
            p.x = pack2(xv.x, xv.y);
            p.y = pack2(xv.z, xv.w);
            *(uint2*)&xbf[(size_t)t * HIDDEN + d4 * 4] = p;
        }
#pragma unroll
        for (int e = 0; e < NUM_EXPERTS; ++e) {
            float4 wv = ((const float4*)(Wr + e * HIDDEN))[d4];
            acc[e] += xv.x * wv.x + xv.y * wv.y + xv.z * wv.z + xv.w * wv.w;
        }
    }
#pragma unroll
    for (int e = 0; e < NUM_EXPERTS; ++e)
        for (int o = 32; o > 0; o >>= 1)
            acc[e] += __shfl_xor(acc[e], o, 64);
    __shared__ float red[4][NUM_EXPERTS];
    int wid = threadIdx.x >> 6, lid = threadIdx.x & 63;
    if (lid == 0) {
#pragma unroll
        for (int e = 0; e < NUM_EXPERTS; ++e) red[wid][e] = acc[e];
    }
    __syncthreads();
    if (threadIdx.x == 0) {
        float l[NUM_EXPERTS];
#pragma unroll
        for (int e = 0; e < NUM_EXPERTS; ++e) {
            l[e] = (red[0][e] + red[1][e] + red[2][e] + red[3][e]); // TEMP = 1.0
            logits_out[(size_t)t * NUM_EXPERTS + e] = l[e];
        }
        int i0 = 0; float v0 = l[0];
#pragma unroll
        for (int e = 1; e < NUM_EXPERTS; ++e)
            if (l[e] > v0) { v0 = l[e]; i0 = e; }
        int i1 = -1; float v1 = -1e30f;
#pragma unroll
        for (int e = 0; e < NUM_EXPERTS; ++e) {
            if (e == i0) continue;
            if (i1 < 0 || l[e] > v1) { v1 = l[e]; i1 = e; }
        }
        float e1 = expf(v1 - v0);
        float inv = 1.0f / (1.0f + e1);
        topk_idx[t * 2 + 0] = i0;
        topk_idx[t * 2 + 1] = i1;
        topk_w[t * 2 + 0] = inv;
        topk_w[t * 2 + 1] = e1 * inv;
        atomicAdd(&cnt[i0], 1);
        atomicAdd(&cnt[i1], 1);
    }
}

// ---------------- Setup (scan + init) ----------------
__global__ __launch_bounds__(256) void setup_kernel(
    const int* __restrict__ cnt, int* __restrict__ cursor,
    int* __restrict__ tile_expert, int* __restrict__ row_token,
    float* __restrict__ row_weight)
{
    if (threadIdx.x == 0) {
        int tot = 0;
        for (int e = 0; e < NUM_EXPERTS; ++e) {
            cursor[e] = tot;
            int pc = ((cnt[e] + BM - 1) / BM) * BM;
            int t0 = tot / BM, t1 = (tot + pc) / BM;
            for (int t = t0; t < t1; ++t) tile_expert[t] = e;
            tot += pc;
        }
        for (int t = tot / BM; t < TILES_M; ++t) tile_expert[t] = 0;
    }
    for (int r = threadIdx.x; r < MPAD; r += 256) {
        row_token[r] = -1;
        row_weight[r] = 0.f;
    }
}

// ---------------- Scatter ----------------
__global__ __launch_bounds__(256) void scatter_kernel(
    const int* __restrict__ topk_idx, const float* __restrict__ topk_w,
    int* __restrict__ cursor, int* __restrict__ row_token,
    float* __restrict__ row_weight)
{
    int t = blockIdx.x * 256 + threadIdx.x;
    if (t >= NTOK) return;
#pragma unroll
    for (int k = 0; k < TOPK; ++k) {
        int e = topk_idx[t * 2 + k];
        float w = topk_w[t * 2 + k];
        int pos = atomicAdd(&cursor[e], 1);
        row_token[pos] = t;
        row_weight[pos] = w;
    }
}

// ================= FAST PATH (needs ~136.5 MB ws) =================
// A,Bg,Bu staged via global_load_lds(16B) with pre-swizzled global source
// (chunk c reads source chunk c^(r&7)); MFMA frag reads use the XOR-swizzled
// index, so both sides share the same involution (rule #21).
__global__ __launch_bounds__(256) void gemm1_fast(
    const ushort* __restrict__ xbf, const ushort* __restrict__ Wgb,
    const ushort* __restrict__ Wub, const int* __restrict__ row_token,
    const int* __restrict__ tile_expert, ushort* __restrict__ H)
{
    int mtile = blockIdx.x, ntile = blockIdx.y;
    int e = tile_expert[mtile];
    __shared__ __align__(16) ushort As[BM * BK];
    __shared__ __align__(16) ushort Bgs[BM * BK];
    __shared__ __align__(16) ushort Bus[BM * BK];
    int tid = threadIdx.x;
    int rsub = tid >> 3, cc = tid & 7;

    const ushort* aSrc[4];
    const ushort* gSrc[4];
    const ushort* uSrc[4];
#pragma unroll
    for (int it = 0; it < 4; ++it) {
        int r = it * 32 + rsub;
        int tok = row_token[mtile * BM + r];
        if (tok < 0) tok = 0;  // padding rows: finite garbage, masked later
        int csw = (cc ^ (r & 7)) * 8;
        aSrc[it] = xbf + (size_t)tok * HIDDEN + csw;
        size_t brow = (size_t)e * INTER + (size_t)ntile * BM + r;
        gSrc[it] = Wgb + brow * HIDDEN + csw;
        uSrc[it] = Wub + brow * HIDDEN + csw;
    }

    f32x4 accG[4][4], accU[4][4];
#pragma unroll
    for (int mi = 0; mi < 4; ++mi)
#pragma unroll
        for (int nj = 0; nj < 4; ++nj) {
            accG[mi][nj] = (f32x4){0.f, 0.f, 0.f, 0.f};
            accU[mi][nj] = (f32x4){0.f, 0.f, 0.f, 0.f};
        }

    int lid = tid & 63, wid = tid >> 6;
    int wm = (wid >> 1) * 64, wn = (wid & 1) * 64;
    int lrow = lid & 15, kg = lid >> 4;

    for (int kk = 0; kk < HIDDEN; kk += BK) {
        __syncthreads();
#pragma unroll
        for (int it = 0; it < 4; ++it) {
            gload_lds16(aSrc[it] + kk, &As[it * 2048 + tid * 8]);
            gload_lds16(gSrc[it] + kk, &Bgs[it * 2048 + tid * 8]);
            gload_lds16(uSrc[it] + kk, &Bus[it * 2048 + tid * 8]);
        }
        __syncthreads();
#pragma unroll
        for (int ks = 0; ks < 2; ++ks) {
            bf16x8 a[4], bg[4], bu[4];
            int kcol = ks * 32 + kg * 8;
#pragma unroll
            for (int mi = 0; mi < 4; ++mi) {
                int r = wm + mi * 16 + lrow;
                a[mi] = *(const bf16x8*)&As[(r * BK + kcol) ^ ((r & 7) << 3)];
            }
#pragma unroll
            for (int nj = 0; nj < 4; ++nj) {
                int r = wn + nj * 16 + lrow;
                int idx = (r * BK + kcol) ^ ((r & 7) << 3);
                bg[nj] = *(const bf16x8*)&Bgs[idx];
                bu[nj] = *(const bf16x8*)&Bus[idx];
            }
#pragma unroll
            for (int mi = 0; mi < 4; ++mi)
#pragma unroll
                for (int nj = 0; nj < 4; ++nj) {
                    accG[mi][nj] = __builtin_amdgcn_mfma_f32_16x16x32_bf16(
                        a[mi], bg[nj], accG[mi][nj], 0, 0, 0);
                    accU[mi][nj] = __builtin_amdgcn_mfma_f32_16x16x32_bf16(
                        a[mi], bu[nj], accU[mi][nj], 0, 0, 0);
                }
        }
    }
#pragma unroll
    for (int mi = 0; mi < 4; ++mi)
#pragma unroll
        for (int nj = 0; nj < 4; ++nj)
#pragma unroll
            for (int q = 0; q < 4; ++q) {
                int row = mtile * BM + wm + mi * 16 + kg * 4 + q;
                int col = ntile * BM + wn + nj * 16 + lrow;
                float g = accG[mi][nj][q], u = accU[mi][nj][q];
                float h = (g / (1.0f + expf(-g))) * u;
                H[(size_t)row * INTER + col] = f2bf(h);
            }
}

__global__ __launch_bounds__(256) void gemm2_fast(
    const ushort* __restrict__ H, const ushort* __restrict__ Wdb,
    const int* __restrict__ row_token, const float* __restrict__ row_weight,
    const int* __restrict__ tile_expert, float* __restrict__ out)
{
    int mtile = blockIdx.x, ntile = blockIdx.y;
    int e = tile_expert[mtile];
    __shared__ __align__(16) ushort As[BM * BK];
    __shared__ __align__(16) ushort Bs[BM * BK];
    __shared__ int s_tok[BM];
    __shared__ float s_w[BM];
    int tid = threadIdx.x;
    if (tid < BM) {
        s_tok[tid] = row_token[mtile * BM + tid];
        s_w[tid] = row_weight[mtile * BM + tid];
    }
    int rsub = tid >> 3, cc = tid & 7;

    const ushort* aSrc[4];
    const ushort* bSrc[4];
#pragma unroll
    for (int it = 0; it < 4; ++it) {
        int r = it * 32 + rsub;
        int csw = (cc ^ (r & 7)) * 8;
        aSrc[it] = H + (size_t)(mtile * BM + r) * INTER + csw;
        size_t brow = (size_t)e * HIDDEN + (size_t)ntile * BM + r;
        bSrc[it] = Wdb + brow * INTER + csw;
    }

    f32x4 acc[4][4];
#pragma unroll
    for (int mi = 0; mi < 4; ++mi)
#pragma unroll
        for (int nj = 0; nj < 4; ++nj)
            acc[mi][nj] = (f32x4){0.f, 0.f, 0.f, 0.f};

    int lid = tid & 63, wid = tid >> 6;
    int wm = (wid >> 1) * 64, wn = (wid & 1) * 64;
    int lrow = lid & 15, kg = lid >> 4;

    for (int kk = 0; kk < INTER; kk += BK) {
        __syncthreads();
#pragma unroll
        for (int it = 0; it < 4; ++it) {
            gload_lds16(aSrc[it] + kk, &As[it * 2048 + tid * 8]);
            gload_lds16(bSrc[it] + kk, &Bs[it * 2048 + tid * 8]);
        }
        __syncthreads();
#pragma unroll
        for (int ks = 0; ks < 2; ++ks) {
            bf16x8 a[4], b[4];
            int kcol = ks * 32 + kg * 8;
#pragma unroll
            for (int mi = 0; mi < 4; ++mi) {
                int r = wm + mi * 16 + lrow;
                a[mi] = *(const bf16x8*)&As[(r * BK + kcol) ^ ((r & 7) << 3)];
            }
#pragma unroll
            for (int nj = 0; nj < 4; ++nj) {
                int r = wn + nj * 16 + lrow;
                b[nj] = *(const bf16x8*)&Bs[(r * BK + kcol) ^ ((r & 7) << 3)];
            }
#pragma unroll
            for (int mi = 0; mi < 4; ++mi)
#pragma unroll
                for (int nj = 0; nj < 4; ++nj)
                    acc[mi][nj] = __builtin_amdgcn_mfma_f32_16x16x32_bf16(
                        a[mi], b[nj], acc[mi][nj], 0, 0, 0);
        }
    }
#pragma unroll
    for (int mi = 0; mi < 4; ++mi)
#pragma unroll
        for (int nj = 0; nj < 4; ++nj)
#pragma unroll
            for (int q = 0; q < 4; ++q) {
                int lrow_local = wm + mi * 16 + kg * 4 + q;
                int tok = s_tok[lrow_local];
                if (tok >= 0) {
                    int col = ntile * BM + wn + nj * 16 + lrow;
                    float val = acc[mi][nj][q] * s_w[lrow_local];
                    atomicAdd(&out[(size_t)tok * HIDDEN + col], val);
                }
            }
}

// ================= FALLBACK PATH (round-1, ~19 MB ws, proven) =================
__global__ __launch_bounds__(256) void gemm1_slow(
    const float* __restrict__ x, const float* __restrict__ Wg,
    const float* __restrict__ Wu, const int* __restrict__ row_token,
    const int* __restrict__ tile_expert, ushort* __restrict__ H)
{
    int mtile = blockIdx.x, ntile = blockIdx.y;
    int e = tile_expert[mtile];
    __shared__ ushort As[BM * BK];
    __shared__ ushort Bgs[BM * BK];
    __shared__ ushort Bus[BM * BK];
    __shared__ int s_tok[BM];
    int tid = threadIdx.x;
    if (tid < BM) s_tok[tid] = row_token[mtile * BM + tid];

    const float* WgB = Wg + (size_t)e * INTER * HIDDEN + (size_t)(ntile * BM) * HIDDEN;
    const float* WuB = Wu + (size_t)e * INTER * HIDDEN + (size_t)(ntile * BM) * HIDDEN;

    f32x4 accG[4][4], accU[4][4];
#pragma unroll
    for (int mi = 0; mi < 4; ++mi)
#pragma unroll
        for (int nj = 0; nj < 4; ++nj) {
            accG[mi][nj] = (f32x4){0.f, 0.f, 0.f, 0.f};
            accU[mi][nj] = (f32x4){0.f, 0.f, 0.f, 0.f};
        }

    int lid = tid & 63, wid = tid >> 6;
    int wm = (wid >> 1) * 64, wn = (wid & 1) * 64;
    int lrow = lid & 15, kg = lid >> 4;

    for (int kk = 0; kk < HIDDEN; kk += BK) {
        __syncthreads();
#pragma unroll
        for (int it = 0; it < 8; ++it) {
            int i = it * 256 + tid;
            int r = i >> 4, c = (i & 15) * 4;
            int tok = s_tok[r];
            float4 v = make_float4(0.f, 0.f, 0.f, 0.f);
            if (tok >= 0)
                v = *(const float4*)(x + (size_t)tok * HIDDEN + kk + c);
            uint2 p;
            p.x = pack2(v.x, v.y);
            p.y = pack2(v.z, v.w);
            int idx = (r * BK + c) ^ ((r & 7) << 3);
            *(uint2*)&As[idx] = p;
        }
#pragma unroll
        for (int it = 0; it < 8; ++it) {
            int i = it * 256 + tid;
            int r = i >> 4, c = (i & 15) * 4;
            float4 vg = *(const float4*)(WgB + (size_t)r * HIDDEN + kk + c);
            float4 vu = *(const float4*)(WuB + (size_t)r * HIDDEN + kk + c);
            int idx = (r * BK + c) ^ ((r & 7) << 3);
            uint2 pg, pu;
            pg.x = pack2(vg.x, vg.y);
            pg.y = pack2(vg.z, vg.w);
            pu.x = pack2(vu.x, vu.y);
            pu.y = pack2(vu.z, vu.w);
            *(uint2*)&Bgs[idx] = pg;
            *(uint2*)&Bus[idx] = pu;
        }
        __syncthreads();
#pragma unroll
        for (int ks = 0; ks < 2; ++ks) {
            bf16x8 a[4], bg[4], bu[4];
            int kcol = ks * 32 + kg * 8;
#pragma unroll
            for (int mi = 0; mi < 4; ++mi) {
                int r = wm + mi * 16 + lrow;
                a[mi] = *(const bf16x8*)&As[(r * BK + kcol) ^ ((r & 7) << 3)];
            }
#pragma unroll
            for (int nj = 0; nj < 4; ++nj) {
                int r = wn + nj * 16 + lrow;
                int idx = (r * BK + kcol) ^ ((r & 7) << 3);
                bg[nj] = *(const bf16x8*)&Bgs[idx];
                bu[nj] = *(const bf16x8*)&Bus[idx];
            }
#pragma unroll
            for (int mi = 0; mi < 4; ++mi)
#pragma unroll
                for (int nj = 0; nj < 4; ++nj) {
                    accG[mi][nj] = __builtin_amdgcn_mfma_f32_16x16x32_bf16(
                        a[mi], bg[nj], accG[mi][nj], 0, 0, 0);
                    accU[mi][nj] = __builtin_amdgcn_mfma_f32_16x16x32_bf16(
                        a[mi], bu[nj], accU[mi][nj], 0, 0, 0);
                }
        }
    }
#pragma unroll
    for (int mi = 0; mi < 4; ++mi)
#pragma unroll
        for (int nj = 0; nj < 4; ++nj)
#pragma unroll
            for (int q = 0; q < 4; ++q) {
                int row = mtile * BM + wm + mi * 16 + kg * 4 + q;
                int col = ntile * BM + wn + nj * 16 + lrow;
                float g = accG[mi][nj][q], u = accU[mi][nj][q];
                float h = (g / (1.0f + expf(-g))) * u;
                H[(size_t)row * INTER + col] = f2bf(h);
            }
}

__global__ __launch_bounds__(256) void gemm2_slow(
    const ushort* __restrict__ H, const float* __restrict__ Wd,
    const int* __restrict__ row_token, const float* __restrict__ row_weight,
    const int* __restrict__ tile_expert, float* __restrict__ out)
{
    int mtile = blockIdx.x, ntile = blockIdx.y;
    int e = tile_expert[mtile];
    __shared__ ushort As[BM * BK];
    __shared__ ushort Bs[BM * BK];
    __shared__ int s_tok[BM];
    __shared__ float s_w[BM];
    int tid = threadIdx.x;
    if (tid < BM) {
        s_tok[tid] = row_token[mtile * BM + tid];
        s_w[tid] = row_weight[mtile * BM + tid];
    }

    const float* WdB = Wd + (size_t)e * HIDDEN * INTER + (size_t)(ntile * BM) * INTER;

    f32x4 acc[4][4];
#pragma unroll
    for (int mi = 0; mi < 4; ++mi)
#pragma unroll
        for (int nj = 0; nj < 4; ++nj)
            acc[mi][nj] = (f32x4){0.f, 0.f, 0.f, 0.f};

    int lid = tid & 63, wid = tid >> 6;
    int wm = (wid >> 1) * 64, wn = (wid & 1) * 64;
    int lrow = lid & 15, kg = lid >> 4;

    for (int kk = 0; kk < INTER; kk += BK) {
        __syncthreads();
#pragma unroll
        for (int it = 0; it < 4; ++it) {
            int i = it * 256 + tid;
            int r = i >> 3, c = (i & 7) * 8;
            uint4 v = *(const uint4*)(H + (size_t)(mtile * BM + r) * INTER + kk + c);
            int idx = (r * BK + c) ^ ((r & 7) << 3);
            *(uint4*)&As[idx] = v;
        }
#pragma unroll
        for (int it = 0; it < 8; ++it) {
            int i = it * 256 + tid;
            int r = i >> 4, c = (i & 15) * 4;
            float4 v = *(const float4*)(WdB + (size_t)r * INTER + kk + c);
            int idx = (r * BK + c) ^ ((r & 7) << 3);
            uint2 p;
            p.x = pack2(v.x, v.y);
            p.y = pack2(v.z, v.w);
            *(uint2*)&Bs[idx] = p;
        }
        __syncthreads();
#pragma unroll
        for (int ks = 0; ks < 2; ++ks) {
            bf16x8 a[4], b[4];
            int kcol = ks * 32 + kg * 8;
#pragma unroll
            for (int mi = 0; mi < 4; ++mi) {
                int r = wm + mi * 16 + lrow;
                a[mi] = *(const bf16x8*)&As[(r * BK + kcol) ^ ((r & 7) << 3)];
            }
#pragma unroll
            for (int nj = 0; nj < 4; ++nj) {
                int r = wn + nj * 16 + lrow;
                b[nj] = *(const bf16x8*)&Bs[(r * BK + kcol) ^ ((r & 7) << 3)];
            }
#pragma unroll
            for (int mi = 0; mi < 4; ++mi)
#pragma unroll
                for (int nj = 0; nj < 4; ++nj)
                    acc[mi][nj] = __builtin_amdgcn_mfma_f32_16x16x32_bf16(
                        a[mi], b[nj], acc[mi][nj], 0, 0, 0);
        }
    }
#pragma unroll
    for (int mi = 0; mi < 4; ++mi)
#pragma unroll
        for (int nj = 0; nj < 4; ++nj)
#pragma unroll
            for (int q = 0; q < 4; ++q) {
                int lrow_local = wm + mi * 16 + kg * 4 + q;
                int tok = s_tok[lrow_local];
                if (tok >= 0) {
                    int col = ntile * BM + wn + nj * 16 + lrow;
                    float val = acc[mi][nj][q] * s_w[lrow_local];
                    atomicAdd(&out[(size_t)tok * HIDDEN + col], val);
                }
            }
}

extern "C" void kernel_launch(void* const* d_in, const int* in_sizes, int n_in,
                              void* d_out, int out_size, void* d_ws, size_t ws_size,
                              hipStream_t stream) {
    const float* x  = (const float*)d_in[0];
    const float* Wr = (const float*)d_in[1];
    const float* Wg = (const float*)d_in[2];
    const float* Wu = (const float*)d_in[3];
    const float* Wd = (const float*)d_in[4];
    float* out = (float*)d_out;
    float* logits = out + (size_t)NTOK * HIDDEN;

    char* ws = (char*)d_ws;
    int*    cnt         = (int*)(ws + 0);
    int*    cursor      = (int*)(ws + 64);
    int*    tile_expert = (int*)(ws + 128);
    int*    topk_idx    = (int*)(ws + 512);
    float*  topk_w      = (float*)(ws + 33280);
    int*    row_token   = (int*)(ws + 66048);
    float*  row_weight  = (float*)(ws + 102912);

    const size_t FAST_NEED = 136462336ull;   // xbf+H+3 bf16 weight copies
    bool fast = ws_size >= FAST_NEED;

    hipMemsetAsync(d_out, 0, (size_t)out_size * sizeof(float), stream);
    hipMemsetAsync(d_ws, 0, 128, stream);

    if (fast) {
        ushort* xbf = (ushort*)(ws + 147456);            // 16 MB
        ushort* H   = (ushort*)(ws + 16924672);          // 18.9 MB
        ushort* Wgb = (ushort*)(ws + 35799040);          // 32 MB
        ushort* Wub = (ushort*)(ws + 69353472);          // 32 MB
        ushort* Wdb = (ushort*)(ws + 102907904);         // 32 MB -> ends ~136.5 MB

        convert_kernel<<<dim3(4096, 3), 256, 0, stream>>>(Wg, Wu, Wd, Wgb, Wub, Wdb);
        router_kernel<<<NTOK, 256, 0, stream>>>(x, Wr, xbf, logits, topk_idx, topk_w, cnt);
        setup_kernel<<<1, 256, 0, stream>>>(cnt, cursor, tile_expert, row_token, row_weight);
        scatter_kernel<<<NTOK / 256, 256, 0, stream>>>(topk_idx, topk_w, cursor, row_token, row_weight);
        gemm1_fast<<<dim3(TILES_M, INTER / BM), 256, 0, stream>>>(xbf, Wgb, Wub, row_token, tile_expert, H);
        gemm2_fast<<<dim3(TILES_M, HIDDEN / BM), 256, 0, stream>>>(H, Wdb, row_token, row_weight, tile_expert, out);
    } else {
        ushort* H = (ushort*)(ws + 147456);              // 18.9 MB, proven footprint
        router_kernel<<<NTOK, 256, 0, stream>>>(x, Wr, (ushort*)nullptr, logits, topk_idx, topk_w, cnt);
        setup_kernel<<<1, 256, 0, stream>>>(cnt, cursor, tile_expert, row_token, row_weight);
        scatter_kernel<<<NTOK / 256, 256, 0, stream>>>(topk_idx, topk_w, cursor, row_token, row_weight);
        gemm1_slow<<<dim3(TILES_M, INTER / BM), 256, 0, stream>>>(x, Wg, Wu, row_token, tile_expert, H);
        gemm2_slow<<<dim3(TILES_M, HIDDEN / BM), 256, 0, stream>>>(H, Wd, row_token, row_weight, tile_expert, out);
    }
}

// Round 5
// 559.419 us; speedup vs baseline: 1.5882x; 1.2087x over previous
//
#include <hip/hip_runtime.h>
#include <hip/hip_bf16.h>

#define NUM_EXPERTS 8
#define HIDDEN 2048
#define INTER 1024
#define NTOK 4096
#define TOPK 2
#define BM 128
#define BK 64
#define MPAD 9216      // 72 tiles of 128
#define TILES_M 72

typedef __attribute__((ext_vector_type(8))) short bf16x8;
typedef __attribute__((ext_vector_type(4))) float f32x4;

typedef const __attribute__((address_space(1))) unsigned char* gptr_u8;
typedef __attribute__((address_space(3))) unsigned char* lptr_u8;

static __device__ __forceinline__ void gload_lds16(const void* g, void* l) {
    __builtin_amdgcn_global_load_lds((gptr_u8)g, (lptr_u8)l, 16, 0, 0);
}

static __device__ __forceinline__ unsigned short f2bf(float f) {
    unsigned u = __builtin_bit_cast(unsigned, f);
    unsigned rounding = 0x7fffu + ((u >> 16) & 1u);
    u += rounding;
    return (unsigned short)(u >> 16);
}
static __device__ __forceinline__ unsigned pack2(float a, float b) {
    return (unsigned)f2bf(a) | ((unsigned)f2bf(b) << 16);
}
static __device__ __forceinline__ float bf2f(unsigned short u) {
    return __builtin_bit_cast(float, ((unsigned)u) << 16);
}

// ---------------- Weight convert: fp32 -> bf16 (one pass, fast path only) ---
__global__ __launch_bounds__(256) void convert_kernel(
    const float* __restrict__ Wg, const float* __restrict__ Wu,
    const float* __restrict__ Wd, ushort* __restrict__ Wgb,
    ushort* __restrict__ Wub, ushort* __restrict__ Wdb)
{
    const float* src = (blockIdx.y == 0) ? Wg : (blockIdx.y == 1) ? Wu : Wd;
    ushort* dst = (blockIdx.y == 0) ? Wgb : (blockIdx.y == 1) ? Wub : Wdb;
    size_t idx = (size_t)blockIdx.x * 256 + threadIdx.x;
#pragma unroll
    for (int i = 0; i < 4; ++i) {
        size_t p = idx + (size_t)i * 1048576;
        float4 v = ((const float4*)src)[p];
        uint2 u;
        u.x = pack2(v.x, v.y);
        u.y = pack2(v.z, v.w);
        ((uint2*)dst)[p] = u;
    }
}

// ---------------- Router (+ optional x fp32->bf16) ----------------
__global__ __launch_bounds__(256) void router_kernel(
    const float* __restrict__ x, const float* __restrict__ Wr,
    ushort* __restrict__ xbf, float* __restrict__ logits_out,
    int* __restrict__ topk_idx, float* __restrict__ topk_w, int* __restrict__ cnt)
{
    int t = blockIdx.x;
    const float4* xr = (const float4*)(x + (size_t)t * HIDDEN);
    float acc[NUM_EXPERTS];
#pragma unroll
    for (int e = 0; e < NUM_EXPERTS; ++e) acc[e] = 0.f;
#pragma unroll
    for (int i = 0; i < 2; ++i) {
        int d4 = threadIdx.x + i * 256;
        float4 xv = xr[d4];
        if (xbf) {
            uint2 p;
            p.x = pack2(xv.x, xv.y);
            p.y = pack2(xv.z, xv.w);
            *(uint2*)&xbf[(size_t)t * HIDDEN + d4 * 4] = p;
        }
#pragma unroll
        for (int e = 0; e < NUM_EXPERTS; ++e) {
            float4 wv = ((const float4*)(Wr + e * HIDDEN))[d4];
            acc[e] += xv.x * wv.x + xv.y * wv.y + xv.z * wv.z + xv.w * wv.w;
        }
    }
#pragma unroll
    for (int e = 0; e < NUM_EXPERTS; ++e)
        for (int o = 32; o > 0; o >>= 1)
            acc[e] += __shfl_xor(acc[e], o, 64);
    __shared__ float red[4][NUM_EXPERTS];
    int wid = threadIdx.x >> 6, lid = threadIdx.x & 63;
    if (lid == 0) {
#pragma unroll
        for (int e = 0; e < NUM_EXPERTS; ++e) red[wid][e] = acc[e];
    }
    __syncthreads();
    if (threadIdx.x == 0) {
        float l[NUM_EXPERTS];
#pragma unroll
        for (int e = 0; e < NUM_EXPERTS; ++e) {
            l[e] = (red[0][e] + red[1][e] + red[2][e] + red[3][e]); // TEMP = 1.0
            logits_out[(size_t)t * NUM_EXPERTS + e] = l[e];
        }
        int i0 = 0; float v0 = l[0];
#pragma unroll
        for (int e = 1; e < NUM_EXPERTS; ++e)
            if (l[e] > v0) { v0 = l[e]; i0 = e; }
        int i1 = -1; float v1 = -1e30f;
#pragma unroll
        for (int e = 0; e < NUM_EXPERTS; ++e) {
            if (e == i0) continue;
            if (i1 < 0 || l[e] > v1) { v1 = l[e]; i1 = e; }
        }
        float e1 = expf(v1 - v0);
        float inv = 1.0f / (1.0f + e1);
        topk_idx[t * 2 + 0] = i0;
        topk_idx[t * 2 + 1] = i1;
        topk_w[t * 2 + 0] = inv;
        topk_w[t * 2 + 1] = e1 * inv;
        atomicAdd(&cnt[i0], 1);
        atomicAdd(&cnt[i1], 1);
    }
}

// ---------------- Setup (scan + init) ----------------
__global__ __launch_bounds__(256) void setup_kernel(
    const int* __restrict__ cnt, int* __restrict__ cursor,
    int* __restrict__ tile_expert, int* __restrict__ row_token,
    float* __restrict__ row_weight)
{
    if (threadIdx.x == 0) {
        int tot = 0;
        for (int e = 0; e < NUM_EXPERTS; ++e) {
            cursor[e] = tot;
            int pc = ((cnt[e] + BM - 1) / BM) * BM;
            int t0 = tot / BM, t1 = (tot + pc) / BM;
            for (int t = t0; t < t1; ++t) tile_expert[t] = e;
            tot += pc;
        }
        for (int t = tot / BM; t < TILES_M; ++t) tile_expert[t] = 0;
    }
    for (int r = threadIdx.x; r < MPAD; r += 256) {
        row_token[r] = -1;
        row_weight[r] = 0.f;
    }
}

// ---------------- Scatter (also packs row pos into topk_idx hi-bits) --------
__global__ __launch_bounds__(256) void scatter_kernel(
    const int* __restrict__ topk_idx_in, const float* __restrict__ topk_w,
    int* __restrict__ cursor, int* __restrict__ row_token,
    float* __restrict__ row_weight, int* __restrict__ topk_idx_out)
{
    int t = blockIdx.x * 256 + threadIdx.x;
    if (t >= NTOK) return;
#pragma unroll
    for (int k = 0; k < TOPK; ++k) {
        int e = topk_idx_in[t * 2 + k] & 15;
        float w = topk_w[t * 2 + k];
        int pos = atomicAdd(&cursor[e], 1);
        row_token[pos] = t;
        row_weight[pos] = w;
        topk_idx_out[t * 2 + k] = (pos << 4) | e;   // pos<9216 fits in 14 bits
    }
}

// ================= FAST PATH =================
// GEMM1: 128M x 64N tile, G+U fused, 32KB LDS, 8 gload_lds/K-step.
// Grid 72*16=1152 flat, XCD-chunked swizzle (1152%8==0).
__global__ __launch_bounds__(256) void gemm1_fast(
    const ushort* __restrict__ xbf, const ushort* __restrict__ Wgb,
    const ushort* __restrict__ Wub, const int* __restrict__ row_token,
    const int* __restrict__ tile_expert, ushort* __restrict__ H)
{
    int bid = blockIdx.x;
    int swz = (bid & 7) * 144 + (bid >> 3);   // XCD-chunked: each XCD gets 9 mtiles
    int mtile = swz >> 4, ntile = swz & 15;
    int e = tile_expert[mtile];
    __shared__ __align__(16) ushort As[BM * BK];        // 16 KB
    __shared__ __align__(16) ushort Bgs[64 * BK];       // 8 KB
    __shared__ __align__(16) ushort Bus[64 * BK];       // 8 KB
    int tid = threadIdx.x;
    int rsub = tid >> 3, cc = tid & 7;

    const ushort* aSrc[4];
    const ushort* gSrc[2];
    const ushort* uSrc[2];
#pragma unroll
    for (int it = 0; it < 4; ++it) {
        int r = it * 32 + rsub;
        int tok = row_token[mtile * BM + r];
        if (tok < 0) tok = 0;  // padding rows: finite garbage, never combined
        int csw = (cc ^ (r & 7)) * 8;
        aSrc[it] = xbf + (size_t)tok * HIDDEN + csw;
    }
#pragma unroll
    for (int it = 0; it < 2; ++it) {
        int r = it * 32 + rsub;
        int csw = (cc ^ (r & 7)) * 8;
        size_t brow = (size_t)e * INTER + (size_t)ntile * 64 + r;
        gSrc[it] = Wgb + brow * HIDDEN + csw;
        uSrc[it] = Wub + brow * HIDDEN + csw;
    }

    f32x4 accG[4][2], accU[4][2];
#pragma unroll
    for (int mi = 0; mi < 4; ++mi)
#pragma unroll
        for (int nj = 0; nj < 2; ++nj) {
            accG[mi][nj] = (f32x4){0.f, 0.f, 0.f, 0.f};
            accU[mi][nj] = (f32x4){0.f, 0.f, 0.f, 0.f};
        }

    int lid = tid & 63, wid = tid >> 6;
    int wm = (wid >> 1) * 64, wn = (wid & 1) * 32;
    int lrow = lid & 15, kg = lid >> 4;

    for (int kk = 0; kk < HIDDEN; kk += BK) {
        __syncthreads();
#pragma unroll
        for (int it = 0; it < 4; ++it)
            gload_lds16(aSrc[it] + kk, &As[it * 2048 + tid * 8]);
#pragma unroll
        for (int it = 0; it < 2; ++it) {
            gload_lds16(gSrc[it] + kk, &Bgs[it * 2048 + tid * 8]);
            gload_lds16(uSrc[it] + kk, &Bus[it * 2048 + tid * 8]);
        }
        __syncthreads();
#pragma unroll
        for (int ks = 0; ks < 2; ++ks) {
            bf16x8 a[4], bg[2], bu[2];
            int kcol = ks * 32 + kg * 8;
#pragma unroll
            for (int mi = 0; mi < 4; ++mi) {
                int r = wm + mi * 16 + lrow;
                a[mi] = *(const bf16x8*)&As[(r * BK + kcol) ^ ((r & 7) << 3)];
            }
#pragma unroll
            for (int nj = 0; nj < 2; ++nj) {
                int r = wn + nj * 16 + lrow;
                int idx = (r * BK + kcol) ^ ((r & 7) << 3);
                bg[nj] = *(const bf16x8*)&Bgs[idx];
                bu[nj] = *(const bf16x8*)&Bus[idx];
            }
#pragma unroll
            for (int mi = 0; mi < 4; ++mi)
#pragma unroll
                for (int nj = 0; nj < 2; ++nj) {
                    accG[mi][nj] = __builtin_amdgcn_mfma_f32_16x16x32_bf16(
                        a[mi], bg[nj], accG[mi][nj], 0, 0, 0);
                    accU[mi][nj] = __builtin_amdgcn_mfma_f32_16x16x32_bf16(
                        a[mi], bu[nj], accU[mi][nj], 0, 0, 0);
                }
        }
    }
#pragma unroll
    for (int mi = 0; mi < 4; ++mi)
#pragma unroll
        for (int nj = 0; nj < 2; ++nj)
#pragma unroll
            for (int q = 0; q < 4; ++q) {
                int row = mtile * BM + wm + mi * 16 + kg * 4 + q;
                int col = ntile * 64 + wn + nj * 16 + lrow;
                float g = accG[mi][nj][q], u = accU[mi][nj][q];
                float h = (g / (1.0f + expf(-g))) * u;
                H[(size_t)row * INTER + col] = f2bf(h);
            }
}

// GEMM2: 128x128 tile, writes unweighted bf16 Y rows (no atomics).
__global__ __launch_bounds__(256) void gemm2_fast(
    const ushort* __restrict__ H, const ushort* __restrict__ Wdb,
    const int* __restrict__ tile_expert, ushort* __restrict__ Y)
{
    int bid = blockIdx.x;
    int swz = (bid & 7) * 144 + (bid >> 3);
    int mtile = swz >> 4, ntile = swz & 15;
    int e = tile_expert[mtile];
    __shared__ __align__(16) ushort As[BM * BK];
    __shared__ __align__(16) ushort Bs[BM * BK];
    int tid = threadIdx.x;
    int rsub = tid >> 3, cc = tid & 7;

    const ushort* aSrc[4];
    const ushort* bSrc[4];
#pragma unroll
    for (int it = 0; it < 4; ++it) {
        int r = it * 32 + rsub;
        int csw = (cc ^ (r & 7)) * 8;
        aSrc[it] = H + (size_t)(mtile * BM + r) * INTER + csw;
        size_t brow = (size_t)e * HIDDEN + (size_t)ntile * BM + r;
        bSrc[it] = Wdb + brow * INTER + csw;
    }

    f32x4 acc[4][4];
#pragma unroll
    for (int mi = 0; mi < 4; ++mi)
#pragma unroll
        for (int nj = 0; nj < 4; ++nj)
            acc[mi][nj] = (f32x4){0.f, 0.f, 0.f, 0.f};

    int lid = tid & 63, wid = tid >> 6;
    int wm = (wid >> 1) * 64, wn = (wid & 1) * 64;
    int lrow = lid & 15, kg = lid >> 4;

    for (int kk = 0; kk < INTER; kk += BK) {
        __syncthreads();
#pragma unroll
        for (int it = 0; it < 4; ++it) {
            gload_lds16(aSrc[it] + kk, &As[it * 2048 + tid * 8]);
            gload_lds16(bSrc[it] + kk, &Bs[it * 2048 + tid * 8]);
        }
        __syncthreads();
#pragma unroll
        for (int ks = 0; ks < 2; ++ks) {
            bf16x8 a[4], b[4];
            int kcol = ks * 32 + kg * 8;
#pragma unroll
            for (int mi = 0; mi < 4; ++mi) {
                int r = wm + mi * 16 + lrow;
                a[mi] = *(const bf16x8*)&As[(r * BK + kcol) ^ ((r & 7) << 3)];
            }
#pragma unroll
            for (int nj = 0; nj < 4; ++nj) {
                int r = wn + nj * 16 + lrow;
                b[nj] = *(const bf16x8*)&Bs[(r * BK + kcol) ^ ((r & 7) << 3)];
            }
#pragma unroll
            for (int mi = 0; mi < 4; ++mi)
#pragma unroll
                for (int nj = 0; nj < 4; ++nj)
                    acc[mi][nj] = __builtin_amdgcn_mfma_f32_16x16x32_bf16(
                        a[mi], b[nj], acc[mi][nj], 0, 0, 0);
        }
    }
#pragma unroll
    for (int mi = 0; mi < 4; ++mi)
#pragma unroll
        for (int nj = 0; nj < 4; ++nj)
#pragma unroll
            for (int q = 0; q < 4; ++q) {
                int row = mtile * BM + wm + mi * 16 + kg * 4 + q;
                int col = ntile * BM + wn + nj * 16 + lrow;
                Y[(size_t)row * HIDDEN + col] = f2bf(acc[mi][nj][q]);
            }
}

// Combine: out[t] = w0*Y[r0] + w1*Y[r1]  (coalesced, writes every element)
__global__ __launch_bounds__(256) void combine_kernel(
    const ushort* __restrict__ Y, const int* __restrict__ topk_idx,
    const float* __restrict__ topk_w, float* __restrict__ out)
{
    int t = blockIdx.x;
    int r0 = topk_idx[t * 2 + 0] >> 4;
    int r1 = topk_idx[t * 2 + 1] >> 4;
    float w0 = topk_w[t * 2 + 0];
    float w1 = topk_w[t * 2 + 1];
    int c = threadIdx.x * 8;
    uint4 y0 = *(const uint4*)&Y[(size_t)r0 * HIDDEN + c];
    uint4 y1 = *(const uint4*)&Y[(size_t)r1 * HIDDEN + c];
    float o[8];
    const unsigned* p0 = (const unsigned*)&y0;
    const unsigned* p1 = (const unsigned*)&y1;
#pragma unroll
    for (int i = 0; i < 4; ++i) {
        o[i * 2]     = w0 * bf2f((ushort)(p0[i] & 0xffff)) + w1 * bf2f((ushort)(p1[i] & 0xffff));
        o[i * 2 + 1] = w0 * bf2f((ushort)(p0[i] >> 16))    + w1 * bf2f((ushort)(p1[i] >> 16));
    }
    float4* dst = (float4*)&out[(size_t)t * HIDDEN + c];
    dst[0] = make_float4(o[0], o[1], o[2], o[3]);
    dst[1] = make_float4(o[4], o[5], o[6], o[7]);
}

// ================= FALLBACK PATH (round-1, ~19 MB ws, proven) =================
__global__ __launch_bounds__(256) void gemm1_slow(
    const float* __restrict__ x, const float* __restrict__ Wg,
    const float* __restrict__ Wu, const int* __restrict__ row_token,
    const int* __restrict__ tile_expert, ushort* __restrict__ H)
{
    int mtile = blockIdx.x, ntile = blockIdx.y;
    int e = tile_expert[mtile];
    __shared__ ushort As[BM * BK];
    __shared__ ushort Bgs[BM * BK];
    __shared__ ushort Bus[BM * BK];
    __shared__ int s_tok[BM];
    int tid = threadIdx.x;
    if (tid < BM) s_tok[tid] = row_token[mtile * BM + tid];

    const float* WgB = Wg + (size_t)e * INTER * HIDDEN + (size_t)(ntile * BM) * HIDDEN;
    const float* WuB = Wu + (size_t)e * INTER * HIDDEN + (size_t)(ntile * BM) * HIDDEN;

    f32x4 accG[4][4], accU[4][4];
#pragma unroll
    for (int mi = 0; mi < 4; ++mi)
#pragma unroll
        for (int nj = 0; nj < 4; ++nj) {
            accG[mi][nj] = (f32x4){0.f, 0.f, 0.f, 0.f};
            accU[mi][nj] = (f32x4){0.f, 0.f, 0.f, 0.f};
        }

    int lid = tid & 63, wid = tid >> 6;
    int wm = (wid >> 1) * 64, wn = (wid & 1) * 64;
    int lrow = lid & 15, kg = lid >> 4;

    for (int kk = 0; kk < HIDDEN; kk += BK) {
        __syncthreads();
#pragma unroll
        for (int it = 0; it < 8; ++it) {
            int i = it * 256 + tid;
            int r = i >> 4, c = (i & 15) * 4;
            int tok = s_tok[r];
            float4 v = make_float4(0.f, 0.f, 0.f, 0.f);
            if (tok >= 0)
                v = *(const float4*)(x + (size_t)tok * HIDDEN + kk + c);
            uint2 p;
            p.x = pack2(v.x, v.y);
            p.y = pack2(v.z, v.w);
            int idx = (r * BK + c) ^ ((r & 7) << 3);
            *(uint2*)&As[idx] = p;
        }
#pragma unroll
        for (int it = 0; it < 8; ++it) {
            int i = it * 256 + tid;
            int r = i >> 4, c = (i & 15) * 4;
            float4 vg = *(const float4*)(WgB + (size_t)r * HIDDEN + kk + c);
            float4 vu = *(const float4*)(WuB + (size_t)r * HIDDEN + kk + c);
            int idx = (r * BK + c) ^ ((r & 7) << 3);
            uint2 pg, pu;
            pg.x = pack2(vg.x, vg.y);
            pg.y = pack2(vg.z, vg.w);
            pu.x = pack2(vu.x, vu.y);
            pu.y = pack2(vu.z, vu.w);
            *(uint2*)&Bgs[idx] = pg;
            *(uint2*)&Bus[idx] = pu;
        }
        __syncthreads();
#pragma unroll
        for (int ks = 0; ks < 2; ++ks) {
            bf16x8 a[4], bg[4], bu[4];
            int kcol = ks * 32 + kg * 8;
#pragma unroll
            for (int mi = 0; mi < 4; ++mi) {
                int r = wm + mi * 16 + lrow;
                a[mi] = *(const bf16x8*)&As[(r * BK + kcol) ^ ((r & 7) << 3)];
            }
#pragma unroll
            for (int nj = 0; nj < 4; ++nj) {
                int r = wn + nj * 16 + lrow;
                int idx = (r * BK + kcol) ^ ((r & 7) << 3);
                bg[nj] = *(const bf16x8*)&Bgs[idx];
                bu[nj] = *(const bf16x8*)&Bus[idx];
            }
#pragma unroll
            for (int mi = 0; mi < 4; ++mi)
#pragma unroll
                for (int nj = 0; nj < 4; ++nj) {
                    accG[mi][nj] = __builtin_amdgcn_mfma_f32_16x16x32_bf16(
                        a[mi], bg[nj], accG[mi][nj], 0, 0, 0);
                    accU[mi][nj] = __builtin_amdgcn_mfma_f32_16x16x32_bf16(
                        a[mi], bu[nj], accU[mi][nj], 0, 0, 0);
                }
        }
    }
#pragma unroll
    for (int mi = 0; mi < 4; ++mi)
#pragma unroll
        for (int nj = 0; nj < 4; ++nj)
#pragma unroll
            for (int q = 0; q < 4; ++q) {
                int row = mtile * BM + wm + mi * 16 + kg * 4 + q;
                int col = ntile * BM + wn + nj * 16 + lrow;
                float g = accG[mi][nj][q], u = accU[mi][nj][q];
                float h = (g / (1.0f + expf(-g))) * u;
                H[(size_t)row * INTER + col] = f2bf(h);
            }
}

__global__ __launch_bounds__(256) void gemm2_slow(
    const ushort* __restrict__ H, const float* __restrict__ Wd,
    const int* __restrict__ row_token, const float* __restrict__ row_weight,
    const int* __restrict__ tile_expert, float* __restrict__ out)
{
    int mtile = blockIdx.x, ntile = blockIdx.y;
    int e = tile_expert[mtile];
    __shared__ ushort As[BM * BK];
    __shared__ ushort Bs[BM * BK];
    __shared__ int s_tok[BM];
    __shared__ float s_w[BM];
    int tid = threadIdx.x;
    if (tid < BM) {
        s_tok[tid] = row_token[mtile * BM + tid];
        s_w[tid] = row_weight[mtile * BM + tid];
    }

    const float* WdB = Wd + (size_t)e * HIDDEN * INTER + (size_t)(ntile * BM) * INTER;

    f32x4 acc[4][4];
#pragma unroll
    for (int mi = 0; mi < 4; ++mi)
#pragma unroll
        for (int nj = 0; nj < 4; ++nj)
            acc[mi][nj] = (f32x4){0.f, 0.f, 0.f, 0.f};

    int lid = tid & 63, wid = tid >> 6;
    int wm = (wid >> 1) * 64, wn = (wid & 1) * 64;
    int lrow = lid & 15, kg = lid >> 4;

    for (int kk = 0; kk < INTER; kk += BK) {
        __syncthreads();
#pragma unroll
        for (int it = 0; it < 4; ++it) {
            int i = it * 256 + tid;
            int r = i >> 3, c = (i & 7) * 8;
            uint4 v = *(const uint4*)(H + (size_t)(mtile * BM + r) * INTER + kk + c);
            int idx = (r * BK + c) ^ ((r & 7) << 3);
            *(uint4*)&As[idx] = v;
        }
#pragma unroll
        for (int it = 0; it < 8; ++it) {
            int i = it * 256 + tid;
            int r = i >> 4, c = (i & 15) * 4;
            float4 v = *(const float4*)(WdB + (size_t)r * INTER + kk + c);
            int idx = (r * BK + c) ^ ((r & 7) << 3);
            uint2 p;
            p.x = pack2(v.x, v.y);
            p.y = pack2(v.z, v.w);
            *(uint2*)&Bs[idx] = p;
        }
        __syncthreads();
#pragma unroll
        for (int ks = 0; ks < 2; ++ks) {
            bf16x8 a[4], b[4];
            int kcol = ks * 32 + kg * 8;
#pragma unroll
            for (int mi = 0; mi < 4; ++mi) {
                int r = wm + mi * 16 + lrow;
                a[mi] = *(const bf16x8*)&As[(r * BK + kcol) ^ ((r & 7) << 3)];
            }
#pragma unroll
            for (int nj = 0; nj < 4; ++nj) {
                int r = wn + nj * 16 + lrow;
                b[nj] = *(const bf16x8*)&Bs[(r * BK + kcol) ^ ((r & 7) << 3)];
            }
#pragma unroll
            for (int mi = 0; mi < 4; ++mi)
#pragma unroll
                for (int nj = 0; nj < 4; ++nj)
                    acc[mi][nj] = __builtin_amdgcn_mfma_f32_16x16x32_bf16(
                        a[mi], b[nj], acc[mi][nj], 0, 0, 0);
        }
    }
#pragma unroll
    for (int mi = 0; mi < 4; ++mi)
#pragma unroll
        for (int nj = 0; nj < 4; ++nj)
#pragma unroll
            for (int q = 0; q < 4; ++q) {
                int lrow_local = wm + mi * 16 + kg * 4 + q;
                int tok = s_tok[lrow_local];
                if (tok >= 0) {
                    int col = ntile * BM + wn + nj * 16 + lrow;
                    float val = acc[mi][nj][q] * s_w[lrow_local];
                    atomicAdd(&out[(size_t)tok * HIDDEN + col], val);
                }
            }
}

extern "C" void kernel_launch(void* const* d_in, const int* in_sizes, int n_in,
                              void* d_out, int out_size, void* d_ws, size_t ws_size,
                              hipStream_t stream) {
    const float* x  = (const float*)d_in[0];
    const float* Wr = (const float*)d_in[1];
    const float* Wg = (const float*)d_in[2];
    const float* Wu = (const float*)d_in[3];
    const float* Wd = (const float*)d_in[4];
    float* out = (float*)d_out;
    float* logits = out + (size_t)NTOK * HIDDEN;

    char* ws = (char*)d_ws;
    int*    cnt         = (int*)(ws + 0);
    int*    cursor      = (int*)(ws + 64);
    int*    tile_expert = (int*)(ws + 128);
    int*    topk_idx    = (int*)(ws + 512);
    float*  topk_w      = (float*)(ws + 33280);
    int*    row_token   = (int*)(ws + 66048);
    float*  row_weight  = (float*)(ws + 102912);

    const size_t FAST_NEED = 136462336ull;   // xbf+Wgb+Wub+H+Wdb (Y overlaps dead xbf/Wgb)
    bool fast = ws_size >= FAST_NEED;

    hipMemsetAsync(d_ws, 0, 128, stream);

    if (fast) {
        // Layout: dead-after-gemm1 regions (xbf,Wgb,Wub) first so Y can overlap.
        ushort* xbf = (ushort*)(ws + 147456);            // 16.78 MB -> 16,924,672
        ushort* Wgb = (ushort*)(ws + 16924672);          // 33.55 MB -> 50,479,104
        ushort* Wub = (ushort*)(ws + 50479104);          // 33.55 MB -> 84,033,536
        ushort* H   = (ushort*)(ws + 84033536);          // 18.87 MB -> 102,907,904
        ushort* Wdb = (ushort*)(ws + 102907904);         // 33.55 MB -> 136,462,336
        ushort* Y   = (ushort*)(ws + 147456);            // 37.75 MB, overlaps xbf+Wgb

        convert_kernel<<<dim3(4096, 3), 256, 0, stream>>>(Wg, Wu, Wd, Wgb, Wub, Wdb);
        router_kernel<<<NTOK, 256, 0, stream>>>(x, Wr, xbf, logits, topk_idx, topk_w, cnt);
        setup_kernel<<<1, 256, 0, stream>>>(cnt, cursor, tile_expert, row_token, row_weight);
        scatter_kernel<<<NTOK / 256, 256, 0, stream>>>(topk_idx, topk_w, cursor, row_token, row_weight, topk_idx);
        gemm1_fast<<<TILES_M * 16, 256, 0, stream>>>(xbf, Wgb, Wub, row_token, tile_expert, H);
        gemm2_fast<<<TILES_M * 16, 256, 0, stream>>>(H, Wdb, tile_expert, Y);
        combine_kernel<<<NTOK, 256, 0, stream>>>(Y, topk_idx, topk_w, out);
    } else {
        ushort* H = (ushort*)(ws + 147456);              // proven footprint
        hipMemsetAsync(d_out, 0, (size_t)out_size * sizeof(float), stream);
        router_kernel<<<NTOK, 256, 0, stream>>>(x, Wr, (ushort*)nullptr, logits, topk_idx, topk_w, cnt);
        setup_kernel<<<1, 256, 0, stream>>>(cnt, cursor, tile_expert, row_token, row_weight);
        scatter_kernel<<<NTOK / 256, 256, 0, stream>>>(topk_idx, topk_w, cursor, row_token, row_weight, topk_idx);
        gemm1_slow<<<dim3(TILES_M, INTER / BM), 256, 0, stream>>>(x, Wg, Wu, row_token, tile_expert, H);
        gemm2_slow<<<dim3(TILES_M, HIDDEN / BM), 256, 0, stream>>>(H, Wd, row_token, row_weight, tile_expert, out);
    }
}